// Round 1
// baseline (225.372 us; speedup 1.0000x reference)
//
#include <hip/hip_runtime.h>

#define AS1 __attribute__((address_space(1)))
#define AS3 __attribute__((address_space(3)))

typedef __bf16 bf16x8 __attribute__((ext_vector_type(8)));
typedef float f32x4 __attribute__((ext_vector_type(4)));

// round-to-nearest-even f32 -> bf16 (avoids header API differences)
__device__ __forceinline__ unsigned short f2bf(float f) {
  union { float f; unsigned u; } v; v.f = f;
  unsigned u = v.u;
  unsigned r = (u + 0x7fffu + ((u >> 16) & 1u)) >> 16;
  return (unsigned short)r;
}

// ---------------------------------------------------------------------------
// d[b,o] = rsqrt( sum_i (y[b,i]/32)^2 * W[i,o]^2 + 1e-8 )   (all fp32)
// grid (32, 4), block 256: one (b, 256-wide o chunk) per block.
// ---------------------------------------------------------------------------
__global__ __launch_bounds__(256) void dcalc_kernel(const float* __restrict__ y,
                                                    const float* __restrict__ W,
                                                    float* __restrict__ dmod) {
  __shared__ float ysq[1024];
  const int b = blockIdx.x;
  const int o = blockIdx.y * 256 + threadIdx.x;
  for (int i = threadIdx.x; i < 1024; i += 256) {
    float t = y[b * 1024 + i] * 0.03125f;
    ysq[i] = t * t;
  }
  __syncthreads();
  float acc = 0.f;
#pragma unroll 8
  for (int i = 0; i < 1024; ++i) {
    float w = W[(size_t)i * 1024 + o];
    acc = fmaf(ysq[i], w * w, acc);
  }
  dmod[b * 1024 + o] = rsqrtf(acc + 1e-8f);
}

// ---------------------------------------------------------------------------
// WT[o,i] = bf16(W[i,o])  -- 32x32 LDS tile transpose, grid (32,32), block (32,8)
// ---------------------------------------------------------------------------
__global__ void wconv_kernel(const float* __restrict__ W,
                             unsigned short* __restrict__ WT) {
  __shared__ float t[32][33];
  const int tx = threadIdx.x;
  const int ty = threadIdx.y;
  const int i0 = blockIdx.y * 32;
  const int o0 = blockIdx.x * 32;
#pragma unroll
  for (int k = 0; k < 4; ++k)
    t[ty + k * 8][tx] = W[(size_t)(i0 + ty + k * 8) * 1024 + o0 + tx];
  __syncthreads();
#pragma unroll
  for (int k = 0; k < 4; ++k)
    WT[(size_t)(o0 + ty + k * 8) * 1024 + i0 + tx] = f2bf(t[tx][ty + k * 8]);
}

// ---------------------------------------------------------------------------
// X[m,i] = bf16(Efou[m,i] * y[b,i]/32),  m = b*1024 + s.  float4 -> ushort4.
// ---------------------------------------------------------------------------
__global__ __launch_bounds__(256) void xconv_kernel(const float4* __restrict__ E4,
                                                    const float* __restrict__ y,
                                                    unsigned short* __restrict__ X) {
  const size_t total = (size_t)8388608;  // 32*1024*1024/4
  for (size_t g = (size_t)blockIdx.x * blockDim.x + threadIdx.x; g < total;
       g += (size_t)gridDim.x * blockDim.x) {
    float4 v = E4[g];
    size_t e = g * 4;
    int i = (int)(e & 1023);
    int b = (int)(e >> 20);
    float4 yv = *(const float4*)(y + b * 1024 + i);
    ushort4 o;
    o.x = f2bf(v.x * yv.x * 0.03125f);
    o.y = f2bf(v.y * yv.y * 0.03125f);
    o.z = f2bf(v.z * yv.z * 0.03125f);
    o.w = f2bf(v.w * yv.w * 0.03125f);
    *(ushort4*)(X + e) = o;
  }
}

// ---------------------------------------------------------------------------
// GEMM: out[m, o] = (X @ W) [m, o] * d[m>>10, o]
// X: 32768 x 1024 bf16 row-major, WT: 1024 x 1024 bf16 row-major (W^T, [o][i])
// m97 structure: BM=BN=128, BK=64, 256 thr (4 waves 2x2), global_load_lds x16,
// single-buffered LDS, 2 barriers per K-step, mfma_f32_16x16x32_bf16.
// ---------------------------------------------------------------------------
#define BM 128
#define BN 128
#define BKK 64
#define KDIM 1024
#define NDIM 1024

__global__ __launch_bounds__(256) void gemm_kernel(const unsigned short* __restrict__ X,
                                                   const unsigned short* __restrict__ WT,
                                                   const float* __restrict__ dmod,
                                                   float* __restrict__ out) {
  __shared__ unsigned short As[BM * BKK];  // [row][k], 128 B rows
  __shared__ unsigned short Bs[BN * BKK];  // [col][k], 128 B rows

  const int tid = threadIdx.x;
  const int bid = blockIdx.x;
  const int bm = bid >> 3;  // M tiles: 256
  const int bn = bid & 7;   // N tiles: 8
  const int m0 = bm * BM;
  const int n0 = bn * BN;
  const int w = tid >> 6;
  const int l = tid & 63;
  const int wr = (w >> 1) * 64;  // wave row origin in tile
  const int wc = (w & 1) * 64;   // wave col origin in tile
  const int l15 = l & 15;
  const int lhi = l >> 4;

  f32x4 acc[4][4] = {};

  // staging: LDS linear byte p = r*4096 + tid*16  ->  row = r*32 + tid/8,
  // kbyte = (tid&7)*16 ; global src matches the same (row, kbyte) mapping.
  const char* Xb = (const char*)X + (size_t)(m0 + (tid >> 3)) * 2048 + (tid & 7) * 16;
  const char* Wb = (const char*)WT + (size_t)(n0 + (tid >> 3)) * 2048 + (tid & 7) * 16;
  char* Abase = (char*)As + tid * 16;
  char* Bbase = (char*)Bs + tid * 16;

  for (int kt = 0; kt < KDIM / BKK; ++kt) {
    const int kb = kt * (BKK * 2);
#pragma unroll
    for (int r = 0; r < 4; ++r)
      __builtin_amdgcn_global_load_lds((const AS1 void*)(Xb + (size_t)r * 32 * 2048 + kb),
                                       (AS3 void*)(Abase + r * 4096), 16, 0, 0);
#pragma unroll
    for (int r = 0; r < 4; ++r)
      __builtin_amdgcn_global_load_lds((const AS1 void*)(Wb + (size_t)r * 32 * 2048 + kb),
                                       (AS3 void*)(Bbase + r * 4096), 16, 0, 0);
    __syncthreads();  // drains vmcnt before any wave reads LDS

#pragma unroll
    for (int kk = 0; kk < 2; ++kk) {
      bf16x8 af[4], bfr[4];
#pragma unroll
      for (int m = 0; m < 4; ++m)
        af[m] = *(const bf16x8*)((const char*)As + (wr + m * 16 + l15) * 128 + kk * 64 + lhi * 16);
#pragma unroll
      for (int n = 0; n < 4; ++n)
        bfr[n] = *(const bf16x8*)((const char*)Bs + (wc + n * 16 + l15) * 128 + kk * 64 + lhi * 16);
#pragma unroll
      for (int m = 0; m < 4; ++m)
#pragma unroll
        for (int n = 0; n < 4; ++n)
          acc[m][n] = __builtin_amdgcn_mfma_f32_16x16x32_bf16(af[m], bfr[n], acc[m][n], 0, 0, 0);
    }
    __syncthreads();  // all reads done before next stage overwrites
  }

  // epilogue: C/D layout col = l&15, row = (l>>4)*4 + j  (m89-verified)
  const int b = m0 >> 10;  // BM=128 divides 1024 -> uniform per block
  const float* drow = dmod + b * 1024 + n0 + wc + l15;
  float dv[4];
#pragma unroll
  for (int n = 0; n < 4; ++n) dv[n] = drow[n * 16];

#pragma unroll
  for (int m = 0; m < 4; ++m) {
#pragma unroll
    for (int j = 0; j < 4; ++j) {
      const int row = m0 + wr + m * 16 + lhi * 4 + j;
      float* orow = out + (size_t)row * NDIM + n0 + wc + l15;
#pragma unroll
      for (int n = 0; n < 4; ++n) orow[n * 16] = acc[m][n][j] * dv[n];
    }
  }
}

// ---------------------------------------------------------------------------
extern "C" void kernel_launch(void* const* d_in, const int* in_sizes, int n_in,
                              void* d_out, int out_size, void* d_ws, size_t ws_size,
                              hipStream_t stream) {
  const float* Efou = (const float*)d_in[0];   // 32*1024*1024 fp32
  const float* y    = (const float*)d_in[1];   // 32*1024 fp32
  const float* W    = (const float*)d_in[2];   // 1024*1024 fp32
  float* out = (float*)d_out;                  // 32*1024*1024 fp32

  // workspace layout
  unsigned short* X  = (unsigned short*)d_ws;            // 64 MB bf16
  unsigned short* WT = X + (size_t)32768 * 1024;         // 2 MB bf16
  float* dmod        = (float*)(WT + (size_t)1024 * 1024);  // 128 KB fp32

  dcalc_kernel<<<dim3(32, 4), 256, 0, stream>>>(y, W, dmod);
  wconv_kernel<<<dim3(32, 32), dim3(32, 8), 0, stream>>>(W, WT);
  xconv_kernel<<<2048, 256, 0, stream>>>((const float4*)Efou, y, X);
  gemm_kernel<<<32768 / BM * (1024 / BN), 256, 0, stream>>>(X, WT, dmod, out);
}

// Round 2
// 214.414 us; speedup vs baseline: 1.0511x; 1.0511x over previous
//
#include <hip/hip_runtime.h>

#define AS1 __attribute__((address_space(1)))
#define AS3 __attribute__((address_space(3)))

typedef __bf16 bf16x8 __attribute__((ext_vector_type(8)));
typedef float f32x4 __attribute__((ext_vector_type(4)));

// round-to-nearest-even f32 -> bf16
__device__ __forceinline__ unsigned short f2bf(float f) {
  union { float f; unsigned u; } v; v.f = f;
  unsigned u = v.u;
  unsigned r = (u + 0x7fffu + ((u >> 16) & 1u)) >> 16;
  return (unsigned short)r;
}

// ---------------------------------------------------------------------------
// d[b,o] = rsqrt( sum_i (y[b,i]/32)^2 * W[i,o]^2 + 1e-8 )   (all fp32)
// 128 blocks, XCD-swizzled so blocks sharing a W column-chunk share an L2.
// ---------------------------------------------------------------------------
__global__ __launch_bounds__(256) void dcalc_kernel(const float* __restrict__ y,
                                                    const float* __restrict__ W,
                                                    float* __restrict__ dmod) {
  __shared__ float ysq[1024];
  const int bid = blockIdx.x;                  // 0..127
  const int wg = (bid & 7) * 16 + (bid >> 3);  // bijective (128 % 8 == 0)
  const int b = wg & 31;
  const int o = (wg >> 5) * 256 + threadIdx.x;
  for (int i = threadIdx.x; i < 1024; i += 256) {
    float t = y[b * 1024 + i] * 0.03125f;
    ysq[i] = t * t;
  }
  __syncthreads();
  float acc = 0.f;
#pragma unroll 8
  for (int i = 0; i < 1024; ++i) {
    float w = W[(size_t)i * 1024 + o];
    acc = fmaf(ysq[i], w * w, acc);
  }
  dmod[b * 1024 + o] = rsqrtf(acc + 1e-8f);
}

// ---------------------------------------------------------------------------
// WT[o,i] = bf16(W[i,o])
// ---------------------------------------------------------------------------
__global__ void wconv_kernel(const float* __restrict__ W,
                             unsigned short* __restrict__ WT) {
  __shared__ float t[32][33];
  const int tx = threadIdx.x;
  const int ty = threadIdx.y;
  const int i0 = blockIdx.y * 32;
  const int o0 = blockIdx.x * 32;
#pragma unroll
  for (int k = 0; k < 4; ++k)
    t[ty + k * 8][tx] = W[(size_t)(i0 + ty + k * 8) * 1024 + o0 + tx];
  __syncthreads();
#pragma unroll
  for (int k = 0; k < 4; ++k)
    WT[(size_t)(o0 + ty + k * 8) * 1024 + i0 + tx] = f2bf(t[tx][ty + k * 8]);
}

// ---------------------------------------------------------------------------
// X[m,i] = bf16(Efou[m,i] * y[b,i]/32)
// ---------------------------------------------------------------------------
__global__ __launch_bounds__(256) void xconv_kernel(const float4* __restrict__ E4,
                                                    const float* __restrict__ y,
                                                    unsigned short* __restrict__ X) {
  const size_t total = (size_t)8388608;  // 32*1024*1024/4
  for (size_t g = (size_t)blockIdx.x * blockDim.x + threadIdx.x; g < total;
       g += (size_t)gridDim.x * blockDim.x) {
    float4 v = E4[g];
    size_t e = g * 4;
    int i = (int)(e & 1023);
    int b = (int)(e >> 20);
    float4 yv = *(const float4*)(y + b * 1024 + i);
    ushort4 o;
    o.x = f2bf(v.x * yv.x * 0.03125f);
    o.y = f2bf(v.y * yv.y * 0.03125f);
    o.z = f2bf(v.z * yv.z * 0.03125f);
    o.w = f2bf(v.w * yv.w * 0.03125f);
    *(ushort4*)(X + e) = o;
  }
}

// ---------------------------------------------------------------------------
// GEMM: out[m,o] = (X @ W)[m,o] * d[m>>10, o]
// 256x256 tile, BK=64, 512 thr (8 waves 2Mx4N), 8-phase schedule (2 K-tiles /
// 8 phases), counted vmcnt, XOR-swizzled LDS, XCD-swizzled blockIdx, setprio.
// ---------------------------------------------------------------------------
#define NT 16          // K / BK
#define LDS_TILE 65536 // per-buffer: A 32KB + B 32KB

#define BAR __builtin_amdgcn_s_barrier()
#define LGKM0 asm volatile("s_waitcnt lgkmcnt(0)" ::: "memory")
#define VM(n) asm volatile("s_waitcnt vmcnt(" #n ")" ::: "memory")
#define SCHB __builtin_amdgcn_sched_barrier(0)
#define PRIO(x) __builtin_amdgcn_s_setprio(x)

// stage one 64-row half (8KB) of A/B for K-tile t into dst buffer
#define STG_A(r, t, dst)                                                     \
  __builtin_amdgcn_global_load_lds(                                          \
      (const AS1 void*)(Xs + (size_t)(r) * 64 * 2048 + (t) * 128),           \
      (AS3 void*)((dst) + (r) * 8192 + sldso), 16, 0, 0)
#define STG_B(r, t, dst)                                                     \
  __builtin_amdgcn_global_load_lds(                                          \
      (const AS1 void*)(Ws + (size_t)(r) * 64 * 2048 + (t) * 128),           \
      (AS3 void*)((dst) + 32768 + (r) * 8192 + sldso), 16, 0, 0)

// swizzled fragment reads (row&7 == l15&7 for all frags)
#define RD_A(mh, mi, kk)                                                     \
  (*(const bf16x8*)(Ab + (wr * 128 + ((mh) * 4 + (mi)) * 16 + l15) * 128 +   \
                    ((((kk) * 64 + lhi * 16)) ^ swz_rd)))
#define RD_B(nh, ni, kk)                                                     \
  (*(const bf16x8*)(Bb + (wc * 64 + ((nh) * 2 + (ni)) * 16 + l15) * 128 +    \
                    ((((kk) * 64 + lhi * 16)) ^ swz_rd)))

#define LD_A(mh)                                                             \
  { _Pragma("unroll") for (int mi = 0; mi < 4; ++mi)                         \
      _Pragma("unroll") for (int kk = 0; kk < 2; ++kk)                       \
        a[mi][kk] = RD_A(mh, mi, kk); }
#define LD_B(nh)                                                             \
  { _Pragma("unroll") for (int ni = 0; ni < 2; ++ni)                         \
      _Pragma("unroll") for (int kk = 0; kk < 2; ++kk)                       \
        bfr[ni][kk] = RD_B(nh, ni, kk); }

#define MM(mh, nh)                                                           \
  do {                                                                       \
    _Pragma("unroll") for (int mi = 0; mi < 4; ++mi)                         \
      _Pragma("unroll") for (int ni = 0; ni < 2; ++ni)                       \
        _Pragma("unroll") for (int kk = 0; kk < 2; ++kk)                     \
          acc[(mh) * 4 + mi][(nh) * 2 + ni] =                                \
              __builtin_amdgcn_mfma_f32_16x16x32_bf16(                       \
                  a[mi][kk], bfr[ni][kk], acc[(mh) * 4 + mi][(nh) * 2 + ni], \
                  0, 0, 0);                                                  \
  } while (0)

__global__ __launch_bounds__(512, 2) void gemm8_kernel(
    const unsigned short* __restrict__ X, const unsigned short* __restrict__ WT,
    const float* __restrict__ dmod, float* __restrict__ out) {
  extern __shared__ char lds[];
  const int tid = threadIdx.x;
  const int bid = blockIdx.x;                  // 0..511
  const int wg = (bid & 7) * 64 + (bid >> 3);  // bijective XCD swizzle
  const int bm = wg >> 2, bn = wg & 3;
  const int m0 = bm * 256, n0 = bn * 256;

  const int w = tid >> 6, l = tid & 63;
  const int wr = w >> 2, wc = w & 3;  // 2M x 4N waves
  const int l15 = l & 15, lhi = l >> 4;
  const int swz_rd = (l15 & 7) << 4;

  // staging: LDS is written linearly (base + lane*16); the SOURCE column is
  // pre-swizzled so a swizzled ds_read returns logical data (rule #21).
  const int srow = tid >> 3;                                  // 0..63
  const int scb = ((tid & 7) << 4) ^ ((srow & 7) << 4);
  const char* Xs = (const char*)X + (size_t)(m0 + srow) * 2048 + scb;
  const char* Ws = (const char*)WT + (size_t)(n0 + srow) * 2048 + scb;
  const int sldso = tid * 16;

  f32x4 acc[8][4] = {};
  bf16x8 a[4][2], bfr[2][2];

  // prologue: stage tile 0, issue order [A0,A2,B0,B1,B2,B3,A1,A3]
  {
    char* d0 = lds;
    STG_A(0, 0, d0); STG_A(2, 0, d0); STG_B(0, 0, d0); STG_B(1, 0, d0);
    STG_B(2, 0, d0); STG_B(3, 0, d0); STG_A(1, 0, d0); STG_A(3, 0, d0);
  }
  VM(2);  // oldest 6 done: A0,A2,B0..B3 of tile 0
  BAR;

  for (int t = 0; t < NT - 1; ++t) {
    const char* Ab = lds + (t & 1) * LDS_TILE;
    const char* Bb = Ab + 32768;
    char* dN = lds + ((t & 1) ^ 1) * LDS_TILE;
    const int t1 = t + 1;
    // phase 1: quadrant (mh0, nh0)
    LD_A(0); LD_B(0);
    STG_A(0, t1, dN); STG_A(2, t1, dN);
    BAR; LGKM0; SCHB; PRIO(1); MM(0, 0); PRIO(0); SCHB; BAR;
    // phase 2: (mh0, nh1)
    LD_B(1);
    STG_B(0, t1, dN); STG_B(1, t1, dN);
    BAR; LGKM0; SCHB; PRIO(1); MM(0, 1); PRIO(0); SCHB;
    VM(4);  // oldest 2 done: A1,A3 of tile t (needed by phase 3 reads)
    BAR;
    // phase 3: (mh1, nh0)
    LD_A(1); LD_B(0);
    STG_B(2, t1, dN); STG_B(3, t1, dN);
    BAR; LGKM0; SCHB; PRIO(1); MM(1, 0); PRIO(0); SCHB; BAR;
    // phase 4: (mh1, nh1)
    LD_B(1);
    STG_A(1, t1, dN); STG_A(3, t1, dN);
    BAR; LGKM0; SCHB; PRIO(1); MM(1, 1); PRIO(0); SCHB;
    VM(2);  // oldest 6 done: A0,A2,B0..B3 of tile t+1 (phases 1-2 needs)
    BAR;
  }

  // peeled last K-tile (no staging; drain)
  {
    const char* Ab = lds + ((NT - 1) & 1) * LDS_TILE;
    const char* Bb = Ab + 32768;
    LD_A(0); LD_B(0);
    BAR; LGKM0; SCHB; PRIO(1); MM(0, 0); PRIO(0); SCHB; BAR;
    LD_B(1);
    BAR; LGKM0; SCHB; PRIO(1); MM(0, 1); PRIO(0); SCHB;
    VM(0);  // A1,A3 of last tile
    BAR;
    LD_A(1); LD_B(0);
    BAR; LGKM0; SCHB; PRIO(1); MM(1, 0); PRIO(0); SCHB; BAR;
    LD_B(1);
    BAR; LGKM0; SCHB; PRIO(1); MM(1, 1); PRIO(0); SCHB;
  }

  // epilogue: C/D frag layout col=l&15, row=(l>>4)*4+j; scale by d[b,o]
  const int b = m0 >> 10;  // 256 | 1024 -> uniform per block
  const int col0 = n0 + wc * 64 + l15;
  float dv[4];
#pragma unroll
  for (int nf = 0; nf < 4; ++nf) dv[nf] = dmod[b * 1024 + col0 + nf * 16];
#pragma unroll
  for (int mf = 0; mf < 8; ++mf) {
#pragma unroll
    for (int j = 0; j < 4; ++j) {
      const int row = m0 + wr * 128 + mf * 16 + lhi * 4 + j;
      float* orow = out + (size_t)row * 1024 + col0;
#pragma unroll
      for (int nf = 0; nf < 4; ++nf) orow[nf * 16] = acc[mf][nf][j] * dv[nf];
    }
  }
}

// ---------------------------------------------------------------------------
extern "C" void kernel_launch(void* const* d_in, const int* in_sizes, int n_in,
                              void* d_out, int out_size, void* d_ws, size_t ws_size,
                              hipStream_t stream) {
  const float* Efou = (const float*)d_in[0];  // 32*1024*1024 fp32
  const float* y    = (const float*)d_in[1];  // 32*1024 fp32
  const float* W    = (const float*)d_in[2];  // 1024*1024 fp32
  float* out = (float*)d_out;

  unsigned short* X  = (unsigned short*)d_ws;               // 64 MB bf16
  unsigned short* WT = X + (size_t)32768 * 1024;            // 2 MB bf16
  float* dmod        = (float*)(WT + (size_t)1024 * 1024);  // 128 KB fp32

  hipFuncSetAttribute((const void*)gemm8_kernel,
                      hipFuncAttributeMaxDynamicSharedMemorySize, 131072);

  dcalc_kernel<<<128, 256, 0, stream>>>(y, W, dmod);
  wconv_kernel<<<dim3(32, 32), dim3(32, 8), 0, stream>>>(W, WT);
  xconv_kernel<<<2048, 256, 0, stream>>>((const float4*)Efou, y, X);
  gemm8_kernel<<<512, 512, 131072, stream>>>(X, WT, dmod, out);
}

// Round 3
// 138.873 us; speedup vs baseline: 1.6229x; 1.5440x over previous
//
#include <hip/hip_runtime.h>

#define AS1 __attribute__((address_space(1)))
#define AS3 __attribute__((address_space(3)))

typedef __bf16 bf16x8 __attribute__((ext_vector_type(8)));
typedef float f32x4 __attribute__((ext_vector_type(4)));

// round-to-nearest-even f32 -> bf16
__device__ __forceinline__ unsigned short f2bf(float f) {
  union { float f; unsigned u; } v; v.f = f;
  unsigned u = v.u;
  unsigned r = (u + 0x7fffu + ((u >> 16) & 1u)) >> 16;
  return (unsigned short)r;
}

// ---------------------------------------------------------------------------
// dcalc stage A: partial[is][b][o] = sum_{i in chunk is} ysq[b,i] * W[i,o]^2
// grid (4 o-chunks, 32 i-chunks), block 256. Each W element read ONCE feeds
// all 32 batches (32 indep FMA chains/thread hide L2/L3 latency).
// ---------------------------------------------------------------------------
__global__ __launch_bounds__(256) void dcalc_a_kernel(const float* __restrict__ y,
                                                      const float* __restrict__ W,
                                                      float* __restrict__ partial) {
  __shared__ float ysq[32][32];  // [i_local][b]
  const int o = blockIdx.x * 256 + threadIdx.x;
  const int i0 = blockIdx.y * 32;
  // stage ysq transposed: e = il*32 + b
  for (int e = threadIdx.x; e < 1024; e += 256) {
    int il = e >> 5, b = e & 31;
    float t = y[b * 1024 + i0 + il] * 0.03125f;
    ysq[il][b] = t * t;
  }
  __syncthreads();

  f32x4 acc[8] = {};
#pragma unroll
  for (int il = 0; il < 32; ++il) {
    float w = W[(size_t)(i0 + il) * 1024 + o];
    float w2 = w * w;
#pragma unroll
    for (int b4 = 0; b4 < 8; ++b4) {
      f32x4 q = *(const f32x4*)&ysq[il][b4 * 4];
#pragma unroll
      for (int k = 0; k < 4; ++k) acc[b4][k] = fmaf(q[k], w2, acc[b4][k]);
    }
  }
  // partial[is][b][o]
  float* p = partial + (size_t)blockIdx.y * 32768 + o;
#pragma unroll
  for (int b4 = 0; b4 < 8; ++b4)
#pragma unroll
    for (int k = 0; k < 4; ++k) p[(b4 * 4 + k) * 1024] = acc[b4][k];
}

// ---------------------------------------------------------------------------
// dcalc stage B: dmod[b,o] = rsqrt( sum_is partial[is][b][o] + 1e-8 )
// ---------------------------------------------------------------------------
__global__ __launch_bounds__(256) void dcalc_b_kernel(const float* __restrict__ partial,
                                                      float* __restrict__ dmod) {
  const int bo = blockIdx.x * 256 + threadIdx.x;  // grid 128 -> 32768 threads
  float acc = 0.f;
#pragma unroll 8
  for (int is = 0; is < 32; ++is) acc += partial[(size_t)is * 32768 + bo];
  dmod[bo] = rsqrtf(acc + 1e-8f);
}

// ---------------------------------------------------------------------------
// WT[o,i] = bf16(W[i,o])
// ---------------------------------------------------------------------------
__global__ void wconv_kernel(const float* __restrict__ W,
                             unsigned short* __restrict__ WT) {
  __shared__ float t[32][33];
  const int tx = threadIdx.x;
  const int ty = threadIdx.y;
  const int i0 = blockIdx.y * 32;
  const int o0 = blockIdx.x * 32;
#pragma unroll
  for (int k = 0; k < 4; ++k)
    t[ty + k * 8][tx] = W[(size_t)(i0 + ty + k * 8) * 1024 + o0 + tx];
  __syncthreads();
#pragma unroll
  for (int k = 0; k < 4; ++k)
    WT[(size_t)(o0 + ty + k * 8) * 1024 + i0 + tx] = f2bf(t[tx][ty + k * 8]);
}

// ---------------------------------------------------------------------------
// X[m,i] = bf16(Efou[m,i] * y[b,i]/32)
// ---------------------------------------------------------------------------
__global__ __launch_bounds__(256) void xconv_kernel(const float4* __restrict__ E4,
                                                    const float* __restrict__ y,
                                                    unsigned short* __restrict__ X) {
  const size_t total = (size_t)8388608;  // 32*1024*1024/4
  for (size_t g = (size_t)blockIdx.x * blockDim.x + threadIdx.x; g < total;
       g += (size_t)gridDim.x * blockDim.x) {
    float4 v = E4[g];
    size_t e = g * 4;
    int i = (int)(e & 1023);
    int b = (int)(e >> 20);
    float4 yv = *(const float4*)(y + b * 1024 + i);
    ushort4 o;
    o.x = f2bf(v.x * yv.x * 0.03125f);
    o.y = f2bf(v.y * yv.y * 0.03125f);
    o.z = f2bf(v.z * yv.z * 0.03125f);
    o.w = f2bf(v.w * yv.w * 0.03125f);
    *(ushort4*)(X + e) = o;
  }
}

// ---------------------------------------------------------------------------
// GEMM: out[m,o] = (X @ W)[m,o] * d[m>>10, o]
// 256x256 tile, BK=64, 512 thr (8 waves 2Mx4N), 8-phase schedule (2 K-tiles /
// 8 phases), counted vmcnt, XOR-swizzled LDS, XCD-swizzled blockIdx, setprio.
// ---------------------------------------------------------------------------
#define NT 16          // K / BK
#define LDS_TILE 65536 // per-buffer: A 32KB + B 32KB

#define BAR __builtin_amdgcn_s_barrier()
#define LGKM0 asm volatile("s_waitcnt lgkmcnt(0)" ::: "memory")
#define VM(n) asm volatile("s_waitcnt vmcnt(" #n ")" ::: "memory")
#define SCHB __builtin_amdgcn_sched_barrier(0)
#define PRIO(x) __builtin_amdgcn_s_setprio(x)

// stage one 64-row half (8KB) of A/B for K-tile t into dst buffer
#define STG_A(r, t, dst)                                                     \
  __builtin_amdgcn_global_load_lds(                                          \
      (const AS1 void*)(Xs + (size_t)(r) * 64 * 2048 + (t) * 128),           \
      (AS3 void*)((dst) + (r) * 8192 + sldso), 16, 0, 0)
#define STG_B(r, t, dst)                                                     \
  __builtin_amdgcn_global_load_lds(                                          \
      (const AS1 void*)(Ws + (size_t)(r) * 64 * 2048 + (t) * 128),           \
      (AS3 void*)((dst) + 32768 + (r) * 8192 + sldso), 16, 0, 0)

// swizzled fragment reads (row&7 == l15&7 for all frags)
#define RD_A(mh, mi, kk)                                                     \
  (*(const bf16x8*)(Ab + (wr * 128 + ((mh) * 4 + (mi)) * 16 + l15) * 128 +   \
                    ((((kk) * 64 + lhi * 16)) ^ swz_rd)))
#define RD_B(nh, ni, kk)                                                     \
  (*(const bf16x8*)(Bb + (wc * 64 + ((nh) * 2 + (ni)) * 16 + l15) * 128 +    \
                    ((((kk) * 64 + lhi * 16)) ^ swz_rd)))

#define LD_A(mh)                                                             \
  { _Pragma("unroll") for (int mi = 0; mi < 4; ++mi)                         \
      _Pragma("unroll") for (int kk = 0; kk < 2; ++kk)                       \
        a[mi][kk] = RD_A(mh, mi, kk); }
#define LD_B(nh)                                                             \
  { _Pragma("unroll") for (int ni = 0; ni < 2; ++ni)                         \
      _Pragma("unroll") for (int kk = 0; kk < 2; ++kk)                       \
        bfr[ni][kk] = RD_B(nh, ni, kk); }

#define MM(mh, nh)                                                           \
  do {                                                                       \
    _Pragma("unroll") for (int mi = 0; mi < 4; ++mi)                         \
      _Pragma("unroll") for (int ni = 0; ni < 2; ++ni)                       \
        _Pragma("unroll") for (int kk = 0; kk < 2; ++kk)                     \
          acc[(mh) * 4 + mi][(nh) * 2 + ni] =                                \
              __builtin_amdgcn_mfma_f32_16x16x32_bf16(                       \
                  a[mi][kk], bfr[ni][kk], acc[(mh) * 4 + mi][(nh) * 2 + ni], \
                  0, 0, 0);                                                  \
  } while (0)

__global__ __launch_bounds__(512, 2) void gemm8_kernel(
    const unsigned short* __restrict__ X, const unsigned short* __restrict__ WT,
    const float* __restrict__ dmod, float* __restrict__ out) {
  extern __shared__ char lds[];
  const int tid = threadIdx.x;
  const int bid = blockIdx.x;                  // 0..511
  const int wg = (bid & 7) * 64 + (bid >> 3);  // bijective XCD swizzle
  const int bm = wg >> 2, bn = wg & 3;
  const int m0 = bm * 256, n0 = bn * 256;

  const int w = tid >> 6, l = tid & 63;
  const int wr = w >> 2, wc = w & 3;  // 2M x 4N waves
  const int l15 = l & 15, lhi = l >> 4;
  const int swz_rd = (l15 & 7) << 4;

  // staging: LDS is written linearly (base + lane*16); the SOURCE column is
  // pre-swizzled so a swizzled ds_read returns logical data (rule #21).
  const int srow = tid >> 3;                                  // 0..63
  const int scb = ((tid & 7) << 4) ^ ((srow & 7) << 4);
  const char* Xs = (const char*)X + (size_t)(m0 + srow) * 2048 + scb;
  const char* Ws = (const char*)WT + (size_t)(n0 + srow) * 2048 + scb;
  const int sldso = tid * 16;

  f32x4 acc[8][4] = {};
  bf16x8 a[4][2], bfr[2][2];

  // prologue: stage tile 0, issue order [A0,A2,B0,B1,B2,B3,A1,A3]
  {
    char* d0 = lds;
    STG_A(0, 0, d0); STG_A(2, 0, d0); STG_B(0, 0, d0); STG_B(1, 0, d0);
    STG_B(2, 0, d0); STG_B(3, 0, d0); STG_A(1, 0, d0); STG_A(3, 0, d0);
  }
  VM(2);  // oldest 6 done: A0,A2,B0..B3 of tile 0
  BAR;

  for (int t = 0; t < NT - 1; ++t) {
    const char* Ab = lds + (t & 1) * LDS_TILE;
    const char* Bb = Ab + 32768;
    char* dN = lds + ((t & 1) ^ 1) * LDS_TILE;
    const int t1 = t + 1;
    // phase 1: quadrant (mh0, nh0)
    LD_A(0); LD_B(0);
    STG_A(0, t1, dN); STG_A(2, t1, dN);
    BAR; LGKM0; SCHB; PRIO(1); MM(0, 0); PRIO(0); SCHB; BAR;
    // phase 2: (mh0, nh1)
    LD_B(1);
    STG_B(0, t1, dN); STG_B(1, t1, dN);
    BAR; LGKM0; SCHB; PRIO(1); MM(0, 1); PRIO(0); SCHB;
    VM(4);  // oldest 2 done: A1,A3 of tile t (needed by phase 3 reads)
    BAR;
    // phase 3: (mh1, nh0)
    LD_A(1); LD_B(0);
    STG_B(2, t1, dN); STG_B(3, t1, dN);
    BAR; LGKM0; SCHB; PRIO(1); MM(1, 0); PRIO(0); SCHB; BAR;
    // phase 4: (mh1, nh1)
    LD_B(1);
    STG_A(1, t1, dN); STG_A(3, t1, dN);
    BAR; LGKM0; SCHB; PRIO(1); MM(1, 1); PRIO(0); SCHB;
    VM(2);  // oldest 6 done: A0,A2,B0..B3 of tile t+1 (phases 1-2 needs)
    BAR;
  }

  // peeled last K-tile (no staging; drain)
  {
    const char* Ab = lds + ((NT - 1) & 1) * LDS_TILE;
    const char* Bb = Ab + 32768;
    LD_A(0); LD_B(0);
    BAR; LGKM0; SCHB; PRIO(1); MM(0, 0); PRIO(0); SCHB; BAR;
    LD_B(1);
    BAR; LGKM0; SCHB; PRIO(1); MM(0, 1); PRIO(0); SCHB;
    VM(0);  // A1,A3 of last tile
    BAR;
    LD_A(1); LD_B(0);
    BAR; LGKM0; SCHB; PRIO(1); MM(1, 0); PRIO(0); SCHB; BAR;
    LD_B(1);
    BAR; LGKM0; SCHB; PRIO(1); MM(1, 1); PRIO(0); SCHB;
  }

  // epilogue: C/D frag layout col=l&15, row=(l>>4)*4+j; scale by d[b,o]
  const int b = m0 >> 10;  // 256 | 1024 -> uniform per block
  const int col0 = n0 + wc * 64 + l15;
  float dv[4];
#pragma unroll
  for (int nf = 0; nf < 4; ++nf) dv[nf] = dmod[b * 1024 + col0 + nf * 16];
#pragma unroll
  for (int mf = 0; mf < 8; ++mf) {
#pragma unroll
    for (int j = 0; j < 4; ++j) {
      const int row = m0 + wr * 128 + mf * 16 + lhi * 4 + j;
      float* orow = out + (size_t)row * 1024 + col0;
#pragma unroll
      for (int nf = 0; nf < 4; ++nf) orow[nf * 16] = acc[mf][nf][j] * dv[nf];
    }
  }
}

// ---------------------------------------------------------------------------
extern "C" void kernel_launch(void* const* d_in, const int* in_sizes, int n_in,
                              void* d_out, int out_size, void* d_ws, size_t ws_size,
                              hipStream_t stream) {
  const float* Efou = (const float*)d_in[0];  // 32*1024*1024 fp32
  const float* y    = (const float*)d_in[1];  // 32*1024 fp32
  const float* W    = (const float*)d_in[2];  // 1024*1024 fp32
  float* out = (float*)d_out;

  unsigned short* X  = (unsigned short*)d_ws;               // 64 MB bf16
  unsigned short* WT = X + (size_t)32768 * 1024;            // 2 MB bf16
  float* dmod        = (float*)(WT + (size_t)1024 * 1024);  // 128 KB fp32
  float* dpart       = dmod + 32768;                        // 4 MB fp32

  hipFuncSetAttribute((const void*)gemm8_kernel,
                      hipFuncAttributeMaxDynamicSharedMemorySize, 131072);

  dcalc_a_kernel<<<dim3(4, 32), 256, 0, stream>>>(y, W, dpart);
  dcalc_b_kernel<<<128, 256, 0, stream>>>(dpart, dmod);
  wconv_kernel<<<dim3(32, 32), dim3(32, 8), 0, stream>>>(W, WT);
  xconv_kernel<<<2048, 256, 0, stream>>>((const float4*)Efou, y, X);
  gemm8_kernel<<<512, 512, 131072, stream>>>(X, WT, dmod, out);
}

// Round 4
// 129.574 us; speedup vs baseline: 1.7393x; 1.0718x over previous
//
#include <hip/hip_runtime.h>

#define AS1 __attribute__((address_space(1)))
#define AS3 __attribute__((address_space(3)))

typedef __bf16 bf16x8 __attribute__((ext_vector_type(8)));
typedef float f32x4 __attribute__((ext_vector_type(4)));
typedef unsigned short ushort8 __attribute__((ext_vector_type(8)));

// round-to-nearest-even f32 -> bf16
__device__ __forceinline__ unsigned short f2bf(float f) {
  union { float f; unsigned u; } v; v.f = f;
  unsigned u = v.u;
  unsigned r = (u + 0x7fffu + ((u >> 16) & 1u)) >> 16;
  return (unsigned short)r;
}

// ---------------------------------------------------------------------------
// dcalc stage A: partial[is][b][o] = sum_{i in chunk is} ysq[b,i] * W[i,o]^2
// ---------------------------------------------------------------------------
__global__ __launch_bounds__(256) void dcalc_a_kernel(const float* __restrict__ y,
                                                      const float* __restrict__ W,
                                                      float* __restrict__ partial) {
  __shared__ float ysq[32][32];  // [i_local][b]
  const int o = blockIdx.x * 256 + threadIdx.x;
  const int i0 = blockIdx.y * 32;
  for (int e = threadIdx.x; e < 1024; e += 256) {
    int il = e >> 5, b = e & 31;
    float t = y[b * 1024 + i0 + il] * 0.03125f;
    ysq[il][b] = t * t;
  }
  __syncthreads();

  f32x4 acc[8] = {};
#pragma unroll
  for (int il = 0; il < 32; ++il) {
    float w = W[(size_t)(i0 + il) * 1024 + o];
    float w2 = w * w;
#pragma unroll
    for (int b4 = 0; b4 < 8; ++b4) {
      f32x4 q = *(const f32x4*)&ysq[il][b4 * 4];
#pragma unroll
      for (int k = 0; k < 4; ++k) acc[b4][k] = fmaf(q[k], w2, acc[b4][k]);
    }
  }
  float* p = partial + (size_t)blockIdx.y * 32768 + o;
#pragma unroll
  for (int b4 = 0; b4 < 8; ++b4)
#pragma unroll
    for (int k = 0; k < 4; ++k) p[(b4 * 4 + k) * 1024] = acc[b4][k];
}

// ---------------------------------------------------------------------------
// dcalc stage B: dmod[b,o] = rsqrt( sum_is partial[is][b][o] + 1e-8 )
// ---------------------------------------------------------------------------
__global__ __launch_bounds__(256) void dcalc_b_kernel(const float* __restrict__ partial,
                                                      float* __restrict__ dmod) {
  const int bo = blockIdx.x * 256 + threadIdx.x;
  float acc = 0.f;
#pragma unroll 8
  for (int is = 0; is < 32; ++is) acc += partial[(size_t)is * 32768 + bo];
  dmod[bo] = rsqrtf(acc + 1e-8f);
}

// ---------------------------------------------------------------------------
// WT[o,i] = bf16(W[i,o])
// ---------------------------------------------------------------------------
__global__ void wconv_kernel(const float* __restrict__ W,
                             unsigned short* __restrict__ WT) {
  __shared__ float t[32][33];
  const int tx = threadIdx.x;
  const int ty = threadIdx.y;
  const int i0 = blockIdx.y * 32;
  const int o0 = blockIdx.x * 32;
#pragma unroll
  for (int k = 0; k < 4; ++k)
    t[ty + k * 8][tx] = W[(size_t)(i0 + ty + k * 8) * 1024 + o0 + tx];
  __syncthreads();
#pragma unroll
  for (int k = 0; k < 4; ++k)
    WT[(size_t)(o0 + ty + k * 8) * 1024 + i0 + tx] = f2bf(t[tx][ty + k * 8]);
}

// ---------------------------------------------------------------------------
// Fused GEMM: out[m,o] = ((Efou*ys) @ W)[m,o] * d[b,o],  b = m>>10.
// A-staging fused: fp32 Efou -> regs -> (*ys, ->bf16) -> swizzled ds_write.
// B: pre-swizzled-source global_load_lds. 256x256 tile, BK=64, 8 waves.
// ---------------------------------------------------------------------------
#define NT 16           // K / BK
#define LDS_TILE 65536  // per-buffer: A 32KB + B 32KB

#define BAR __builtin_amdgcn_s_barrier()
#define LGKM0 asm volatile("s_waitcnt lgkmcnt(0)" ::: "memory")
#define VM(n) asm volatile("s_waitcnt vmcnt(" #n ")" ::: "memory")
#define SCHB __builtin_amdgcn_sched_barrier(0)
#define PRIO(x) __builtin_amdgcn_s_setprio(x)

// stage one 64-row half (8KB) of B for K-tile t into dst buffer
#define STG_B(r, t, dst)                                                     \
  __builtin_amdgcn_global_load_lds(                                          \
      (const AS1 void*)(Ws + (size_t)(r) * 64 * 2048 + (t) * 128),           \
      (AS3 void*)((dst) + 32768 + (r) * 8192 + sldso), 16, 0, 0)

// issue A fp32 loads (4 rows x 8 k) + ys ds_reads for K-tile t
#define A_ISSUE(t)                                                           \
  {                                                                          \
    const float* asrc = Efou + (size_t)(m0 + argp * 4) * 1024 + (t) * 64 + k8; \
    _Pragma("unroll") for (int rr = 0; rr < 4; ++rr) {                       \
      pa[rr][0] = *(const f32x4*)(asrc + rr * 1024);                         \
      pa[rr][1] = *(const f32x4*)(asrc + rr * 1024 + 4);                     \
    }                                                                        \
    yv[0] = *(const f32x4*)(ysS + (t) * 64 + k8);                            \
    yv[1] = *(const f32x4*)(ysS + (t) * 64 + k8 + 4);                        \
  }

// convert (*ys -> bf16) and swizzled ds_write into dst A region
#define A_WRITE(dst)                                                         \
  {                                                                          \
    _Pragma("unroll") for (int rr = 0; rr < 4; ++rr) {                       \
      const int row = argp * 4 + rr;                                         \
      ushort8 ov;                                                            \
      _Pragma("unroll") for (int q = 0; q < 4; ++q) {                        \
        ov[q] = f2bf(pa[rr][0][q] * yv[0][q]);                               \
        ov[q + 4] = f2bf(pa[rr][1][q] * yv[1][q]);                           \
      }                                                                      \
      *(ushort8*)((dst) + row * 128 + ((kslot * 16) ^ ((row & 7) << 4))) = ov; \
    }                                                                        \
  }

// swizzled fragment reads (row&7 == l15&7 for all frags)
#define RD_A(mh, mi, kk)                                                     \
  (*(const bf16x8*)(Ab + (wr * 128 + ((mh) * 4 + (mi)) * 16 + l15) * 128 +   \
                    ((((kk) * 64 + lhi * 16)) ^ swz_rd)))
#define RD_B(nh, ni, kk)                                                     \
  (*(const bf16x8*)(Bb + (wc * 64 + ((nh) * 2 + (ni)) * 16 + l15) * 128 +    \
                    ((((kk) * 64 + lhi * 16)) ^ swz_rd)))

#define LD_A(mh)                                                             \
  { _Pragma("unroll") for (int mi = 0; mi < 4; ++mi)                         \
      _Pragma("unroll") for (int kk = 0; kk < 2; ++kk)                       \
        a[mi][kk] = RD_A(mh, mi, kk); }
#define LD_B(nh)                                                             \
  { _Pragma("unroll") for (int ni = 0; ni < 2; ++ni)                         \
      _Pragma("unroll") for (int kk = 0; kk < 2; ++kk)                       \
        bfr[ni][kk] = RD_B(nh, ni, kk); }

#define MM(mh, nh)                                                           \
  do {                                                                       \
    _Pragma("unroll") for (int mi = 0; mi < 4; ++mi)                         \
      _Pragma("unroll") for (int ni = 0; ni < 2; ++ni)                       \
        _Pragma("unroll") for (int kk = 0; kk < 2; ++kk)                     \
          acc[(mh) * 4 + mi][(nh) * 2 + ni] =                                \
              __builtin_amdgcn_mfma_f32_16x16x32_bf16(                       \
                  a[mi][kk], bfr[ni][kk], acc[(mh) * 4 + mi][(nh) * 2 + ni], \
                  0, 0, 0);                                                  \
  } while (0)

__global__ __launch_bounds__(512, 2) void gemmf_kernel(
    const float* __restrict__ Efou, const float* __restrict__ y,
    const unsigned short* __restrict__ WT, const float* __restrict__ dmod,
    float* __restrict__ out) {
  extern __shared__ char lds[];
  float* ysS = (float*)(lds + 2 * LDS_TILE);  // 4KB ys table

  const int tid = threadIdx.x;
  const int bid = blockIdx.x;                  // 0..511
  const int wg = (bid & 7) * 64 + (bid >> 3);  // bijective XCD swizzle
  const int bm = wg >> 2, bn = wg & 3;
  const int m0 = bm * 256, n0 = bn * 256;
  const int b = m0 >> 10;  // uniform per block (256 | 1024)

  const int w = tid >> 6, l = tid & 63;
  const int wr = w >> 2, wc = w & 3;  // 2M x 4N waves
  const int l15 = l & 15, lhi = l >> 4;
  const int swz_rd = (l15 & 7) << 4;

  // A reg-staging geometry: 4 rows x 8 k per thread
  const int kslot = tid & 7;
  const int k8 = kslot * 8;
  const int argp = tid >> 3;  // 0..63 -> rows argp*4..+4

  // B staging: LDS written linearly; SOURCE column pre-swizzled (rule #21)
  const int srow = tid >> 3;
  const int scb = ((tid & 7) << 4) ^ ((srow & 7) << 4);
  const char* Ws = (const char*)WT + (size_t)(n0 + srow) * 2048 + scb;
  const int sldso = tid * 16;

  f32x4 acc[8][4] = {};
  bf16x8 a[4][2], bfr[2][2];
  f32x4 pa[4][2], yv[2];

  // ---- prologue ----
  {
    float2 yy = *(const float2*)(y + b * 1024 + tid * 2);
    ysS[2 * tid] = yy.x * 0.03125f;
    ysS[2 * tid + 1] = yy.y * 0.03125f;
  }
  __syncthreads();  // publish ysS
  {
    char* d0 = lds;
    STG_B(0, 0, d0); STG_B(1, 0, d0); STG_B(2, 0, d0); STG_B(3, 0, d0);
    A_ISSUE(0);
    A_WRITE(d0);  // auto-waits A-load vmcnt
  }
  VM(0); LGKM0; BAR;

  // ---- main loop ----
  for (int t = 0; t < NT - 1; ++t) {
    const char* Ab = lds + (t & 1) * LDS_TILE;
    const char* Bb = Ab + 32768;
    char* dN = lds + ((t & 1) ^ 1) * LDS_TILE;
    const int t1 = t + 1;
    // phase 1: quadrant (mh0, nh0); issue next A loads + 2 B stages
    LD_A(0); LD_B(0);
    A_ISSUE(t1);
    STG_B(0, t1, dN); STG_B(1, t1, dN);
    BAR; LGKM0; SCHB; PRIO(1); MM(0, 0); PRIO(0); SCHB; BAR;
    // phase 2: (mh0, nh1); 2 more B stages
    LD_B(1);
    STG_B(2, t1, dN); STG_B(3, t1, dN);
    BAR; LGKM0; SCHB; PRIO(1); MM(0, 1); PRIO(0); SCHB; BAR;
    // phase 3: (mh1, nh0)
    LD_A(1); LD_B(0);
    BAR; LGKM0; SCHB; PRIO(1); MM(1, 0); PRIO(0); SCHB; BAR;
    // phase 4: (mh1, nh1); then publish next tile
    LD_B(1);
    BAR; LGKM0; SCHB; PRIO(1); MM(1, 1); PRIO(0); SCHB;
    A_WRITE(dN);   // waits A-load vmcnt automatically; 4 ds_write_b128
    VM(0);         // B gload_lds for t+1 complete
    LGKM0;         // ds_writes visible before publish barrier
    BAR;
  }

  // ---- peeled last K-tile (no staging) ----
  {
    const char* Ab = lds + ((NT - 1) & 1) * LDS_TILE;
    const char* Bb = Ab + 32768;
    LD_A(0); LD_B(0);
    BAR; LGKM0; SCHB; PRIO(1); MM(0, 0); PRIO(0); SCHB; BAR;
    LD_B(1);
    BAR; LGKM0; SCHB; PRIO(1); MM(0, 1); PRIO(0); SCHB; BAR;
    LD_A(1); LD_B(0);
    BAR; LGKM0; SCHB; PRIO(1); MM(1, 0); PRIO(0); SCHB; BAR;
    LD_B(1);
    BAR; LGKM0; SCHB; PRIO(1); MM(1, 1); PRIO(0); SCHB;
  }

  // ---- epilogue: C/D layout col=l&15, row=(l>>4)*4+j; scale by d[b,o] ----
  const int col0 = n0 + wc * 64 + l15;
  float dv[4];
#pragma unroll
  for (int nf = 0; nf < 4; ++nf) dv[nf] = dmod[b * 1024 + col0 + nf * 16];
#pragma unroll
  for (int mf = 0; mf < 8; ++mf) {
#pragma unroll
    for (int j = 0; j < 4; ++j) {
      const int row = m0 + wr * 128 + mf * 16 + lhi * 4 + j;
      float* orow = out + (size_t)row * 1024 + col0;
#pragma unroll
      for (int nf = 0; nf < 4; ++nf) orow[nf * 16] = acc[mf][nf][j] * dv[nf];
    }
  }
}

// ---------------------------------------------------------------------------
extern "C" void kernel_launch(void* const* d_in, const int* in_sizes, int n_in,
                              void* d_out, int out_size, void* d_ws, size_t ws_size,
                              hipStream_t stream) {
  const float* Efou = (const float*)d_in[0];  // 32*1024*1024 fp32
  const float* y    = (const float*)d_in[1];  // 32*1024 fp32
  const float* W    = (const float*)d_in[2];  // 1024*1024 fp32
  float* out = (float*)d_out;

  unsigned short* WT = (unsigned short*)d_ws;               // 2 MB bf16
  float* dmod        = (float*)(WT + (size_t)1024 * 1024);  // 128 KB fp32
  float* dpart       = dmod + 32768;                        // 4 MB fp32

  hipFuncSetAttribute((const void*)gemmf_kernel,
                      hipFuncAttributeMaxDynamicSharedMemorySize, 135168);

  dcalc_a_kernel<<<dim3(4, 32), 256, 0, stream>>>(y, W, dpart);
  dcalc_b_kernel<<<128, 256, 0, stream>>>(dpart, dmod);
  wconv_kernel<<<dim3(32, 32), dim3(32, 8), 0, stream>>>(W, WT);
  gemmf_kernel<<<512, 512, 135168, stream>>>(Efou, y, WT, dmod, out);
}